// Round 17
// baseline (588.058 us; speedup 1.0000x reference)
//
#include <hip/hip_runtime.h>
#include <hip/hip_fp16.h>
#include <math.h>
#include <float.h>

#define LAYERS 3
#define NGRAPH 128
#define NPB 1024
#define NBMAX 256

typedef __attribute__((ext_vector_type(8))) short bf16x8;
typedef __attribute__((ext_vector_type(4))) float f32x4;

union bfr { int4 i; bf16x8 b; };

__device__ __forceinline__ float gelu_f(float x) {
    return 0.5f * x * (1.0f + erff(x * 0.70710678118654752440f));
}

template <int CTRL, int RMASK>
__device__ __forceinline__ float dpp_add(float x) {
    int t = __builtin_amdgcn_update_dpp(0, __float_as_int(x), CTRL, RMASK, 0xF, false);
    return x + __int_as_float(t);
}

// sum over each 16-lane group; result in all 16 lanes
__device__ __forceinline__ float sum16(float v) {
    v = dpp_add<0xB1, 0xF>(v);
    v = dpp_add<0x4E, 0xF>(v);
    v = dpp_add<0x141, 0xF>(v);
    v = dpp_add<0x140, 0xF>(v);
    return v;
}
// sum over each 4-lane quad
__device__ __forceinline__ float sum4(float v) {
    v = dpp_add<0xB1, 0xF>(v);
    v = dpp_add<0x4E, 0xF>(v);
    return v;
}

__device__ __forceinline__ unsigned int f2mono(float f) {
    unsigned int u = __float_as_uint(f);
    return (u & 0x80000000u) ? ~u : (u | 0x80000000u);
}
__device__ __forceinline__ float mono2f(unsigned int u) {
    return (u & 0x80000000u) ? __uint_as_float(u ^ 0x80000000u)
                             : __uint_as_float(~u);
}

__device__ __forceinline__ float2 h2f2(int bits) {
    __half2 h = *reinterpret_cast<__half2*>(&bits);
    return __half22float2(h);
}

__device__ __forceinline__ void cvt_frag(const float4& f0, const float4& f1,
                                         bf16x8& hi, bf16x8& lo) {
    float ff[8] = {f0.x, f0.y, f0.z, f0.w, f1.x, f1.y, f1.z, f1.w};
#pragma unroll
    for (int j = 0; j < 8; j++) {
        unsigned u = __float_as_uint(ff[j]);
        hi[j] = (short)(u >> 16);
        float hf = __uint_as_float(u & 0xFFFF0000u);
        lo[j] = (short)(__float_as_uint(ff[j] - hf) >> 16);
    }
}

__device__ __forceinline__ f32x4 mm3(const bf16x8& ahi, const bf16x8& alo,
                                     const int4* __restrict__ pk, int tile,
                                     int lane, f32x4 acc) {
    bfr bh, bl;
    bh.i = pk[tile * 128 + lane];
    bl.i = pk[tile * 128 + 64 + lane];
    acc = __builtin_amdgcn_mfma_f32_16x16x32_bf16(alo, bh.b, acc, 0, 0, 0);
    acc = __builtin_amdgcn_mfma_f32_16x16x32_bf16(ahi, bl.b, acc, 0, 0, 0);
    acc = __builtin_amdgcn_mfma_f32_16x16x32_bf16(ahi, bh.b, acc, 0, 0, 0);
    return acc;
}

// kv interleaved row: slot (d>>2)*8 + 0..3 = k dims, +4..7 = v dims
__device__ __forceinline__ int kv_idx(int m, int cc) {
    return (cc >> 2) * 8 + (m - 1) * 4 + (cc & 3);
}

// ---------------- weight packing (once per launch) ----------------
__global__ __launch_bounds__(256) void k_cvt(
    const float* __restrict__ in_W, const float* __restrict__ W_skip,
    const float* __restrict__ W_qkv, int4* __restrict__ pk_in,
    int4* __restrict__ pk_skip, int4* __restrict__ pk_qkv) {
    int w = (blockIdx.x * 256 + threadIdx.x) >> 6;
    if (w >= 100) return;
    int lane = threadIdx.x & 63;
    const float* src;
    int4* dst;
    int kt, jt, qkvmode = 0;
    if (w < 4) {
        kt = 0; jt = w;
        src = in_W;
        dst = pk_in + w * 128;
    } else {
        int l = (w - 4) >> 5, r = (w - 4) & 31;
        if (r < 8) {
            kt = r & 1; jt = r >> 1;
            src = W_skip + l * 4096;
            dst = pk_skip + (l * 8 + r) * 128;
        } else {
            int tq = r - 8;
            kt = tq & 1; jt = tq >> 1;
            src = W_qkv + l * 12288;
            dst = pk_qkv + (l * 24 + tq) * 128;
            qkvmode = 1;
        }
    }
    int c = jt * 16 + (lane & 15);
    int koff = kt * 32 + (lane >> 4) * 8;
    unsigned hi[8], lo[8];
#pragma unroll
    for (int j = 0; j < 8; j++) {
        int k = koff + j;
        float f = qkvmode ? src[(c >> 6) * 4096 + k * 64 + (c & 63)]
                          : src[k * 64 + c];
        unsigned u = __float_as_uint(f);
        hi[j] = u >> 16;
        float hf = __uint_as_float(u & 0xFFFF0000u);
        lo[j] = __float_as_uint(f - hf) >> 16;
    }
    int4 H, L;
    H.x = hi[0] | (hi[1] << 16); H.y = hi[2] | (hi[3] << 16);
    H.z = hi[4] | (hi[5] << 16); H.w = hi[6] | (hi[7] << 16);
    L.x = lo[0] | (lo[1] << 16); L.y = lo[2] | (lo[3] << 16);
    L.z = lo[4] | (lo[5] << 16); L.w = lo[6] | (lo[7] << 16);
    dst[lane] = H;
    dst[64 + lane] = L;
}

// ---------------- CSR build ----------------
__global__ __launch_bounds__(256) void k_hist(const int* __restrict__ dst,
                                              int* __restrict__ deg, int E) {
    int e = blockIdx.x * 256 + threadIdx.x;
    if (e < E) atomicAdd(&deg[dst[e]], 1);
}

__global__ __launch_bounds__(256) void k_scan1(const int* __restrict__ deg,
                                               int* __restrict__ excl,
                                               int* __restrict__ bsum, int n) {
    __shared__ int s[256];
    int t = threadIdx.x;
    int i = blockIdx.x * 256 + t;
    int v = (i < n) ? deg[i] : 0;
    s[t] = v;
    __syncthreads();
    for (int off = 1; off < 256; off <<= 1) {
        int a = (t >= off) ? s[t - off] : 0;
        __syncthreads();
        s[t] += a;
        __syncthreads();
    }
    if (i < n) excl[i] = s[t] - v;
    if (t == 255) bsum[blockIdx.x] = s[255];
}

__global__ __launch_bounds__(512) void k_scan2(int* __restrict__ bsum, int nb) {
    __shared__ int s[512];
    int t = threadIdx.x;
    int v = (t < nb) ? bsum[t] : 0;
    s[t] = v;
    __syncthreads();
    for (int off = 1; off < 512; off <<= 1) {
        int a = (t >= off) ? s[t - off] : 0;
        __syncthreads();
        s[t] += a;
        __syncthreads();
    }
    if (t < nb) bsum[t] = s[t] - v;
}

__global__ __launch_bounds__(256) void k_scan3(const int* __restrict__ excl,
                                               const int* __restrict__ bsum,
                                               int* __restrict__ row,
                                               int* __restrict__ cursor,
                                               int* __restrict__ gcurb,
                                               int n, int E) {
    int i = blockIdx.x * 256 + threadIdx.x;
    if (i < n) {
        int r = excl[i] + bsum[blockIdx.x];
        row[i] = r;
        cursor[i] = r;
        if ((i & (NPB - 1)) == 0) gcurb[i >> 10] = r;
    }
    if (blockIdx.x == 0 && threadIdx.x == 0) row[n] = E;
}

__global__ __launch_bounds__(256) void k_bucket(
    const int* __restrict__ src, const int* __restrict__ dst,
    const float* __restrict__ ea, int* __restrict__ gcurb,
    int2* __restrict__ mid, int E, int nbkt) {
    __shared__ int cnt[NBMAX], base_[NBMAX];
    int tile = blockIdx.x * 4096;
    for (int i = threadIdx.x; i < nbkt; i += 256) cnt[i] = 0;
    __syncthreads();
    int d[16];
#pragma unroll
    for (int j = 0; j < 16; j++) {
        int e = tile + j * 256 + threadIdx.x;
        d[j] = -1;
        if (e < E) {
            d[j] = dst[e];
            atomicAdd(&cnt[d[j] >> 10], 1);
        }
    }
    __syncthreads();
    for (int i = threadIdx.x; i < nbkt; i += 256) {
        base_[i] = atomicAdd(&gcurb[i], cnt[i]);
        cnt[i] = 0;
    }
    __syncthreads();
#pragma unroll
    for (int j = 0; j < 16; j++) {
        int e = tile + j * 256 + threadIdx.x;
        if (e < E) {
            int b = d[j] >> 10;
            int p = base_[b] + atomicAdd(&cnt[b], 1);
            mid[p] = make_int2(src[e] | ((d[j] & (NPB - 1)) << 20),
                               __float_as_int(ea[e]));
        }
    }
}

__global__ __launch_bounds__(256) void k_local(
    const int* __restrict__ row, int* __restrict__ cursor,
    const int2* __restrict__ mid, int2* __restrict__ ep, int n) {
    int b = blockIdx.x;
    int n0 = b << 10;
    int n1 = min(n, n0 + NPB);
    int ebeg = row[n0], eend = row[n1];
    for (int e = ebeg + blockIdx.y * 256 + threadIdx.x; e < eend;
         e += 256 * gridDim.y) {
        int2 m = mid[e];
        int dn = n0 + ((m.x >> 20) & (NPB - 1));
        int p = atomicAdd(&cursor[dn], 1);
        ep[p] = make_int2(m.x & 0xFFFFF, m.y);
    }
}

// ============ shared epilogue helper: qkv GEMM + staged vector stores ========
__device__ __forceinline__ void qkv_gemm_store(
    const float* ldsH, float* ldsQf, const int4* __restrict__ pk_qkv,
    const float* __restrict__ bn, __half* __restrict__ q,
    __half* __restrict__ kvout, int nb, int n, int lane, int g16, int c16) {
    // A-frags of hnew from LDS epilogue layout [4][64]
    bf16x8 qahi[2], qalo[2];
#pragma unroll
    for (int kt = 0; kt < 2; kt++) {
        const float* lp = &ldsH[(c16 & 3) * 64 + kt * 32 + g16 * 8];
        float4 t0 = *(const float4*)lp;
        float4 t1 = *(const float4*)(lp + 4);
        cvt_frag(t0, t1, qahi[kt], qalo[kt]);
    }
    __half* ldsQh = reinterpret_cast<__half*>(ldsQf);  // [4][200] halfs
#pragma unroll
    for (int jt = 0; jt < 12; jt++) {
        f32x4 a = {0.f, 0.f, 0.f, 0.f};
#pragma unroll
        for (int kt = 0; kt < 2; kt++)
            a = mm3(qahi[kt], qalo[kt], pk_qkv, jt * 2 + kt, lane, a);
        int c = jt * 16 + c16;
        float bias = bn[c];
        int m = c >> 6, cc = c & 63;
        int colpos = (m == 0) ? cc : (64 + kv_idx(m, cc));
        if (g16 == 0) {
#pragma unroll
            for (int r = 0; r < 4; r++)
                ldsQh[r * 200 + colpos] = __float2half(a[r] + bias);
        }
    }
    __syncthreads();
    if (lane < 32) {
        int row = lane >> 3, ck = lane & 7;
        if (nb + row < n)
            *(int4*)(q + (size_t)(nb + row) * 64 + ck * 8) =
                *(const int4*)&ldsQh[row * 200 + ck * 8];
    }
    {
        int row = lane >> 4, ck = lane & 15;
        if (nb + row < n)
            *(int4*)(kvout + (size_t)(nb + row) * 128 + ck * 8) =
                *(const int4*)&ldsQh[row * 200 + 64 + ck * 8];
    }
}

// ---------------- fused input + layer-0 qkv: 4 nodes per wave ----------------
__global__ __launch_bounds__(64) void k_in_qkv4(
    const float* __restrict__ x, const int4* __restrict__ pk_in,
    const float* __restrict__ b, const float* __restrict__ g,
    const float* __restrict__ be, const int4* __restrict__ pk_qkv,
    const float* __restrict__ bn, float* __restrict__ h,
    __half* __restrict__ q, __half* __restrict__ kvout, int n) {
    __shared__ __align__(16) float ldsH[256];   // hnew epilogue layout [4][64]
    __shared__ __align__(16) float ldsX[256];   // pre-act redistribution
    __shared__ __align__(16) float ldsQf[4][100];
    int lane = threadIdx.x;
    int nb = blockIdx.x * 4;
    if (nb >= n) return;
    int g16 = lane >> 4, c16 = lane & 15;
    int arow = min(nb + (c16 & 3), n - 1);
    // A-frag from x (K=32)
    const float* xp = x + (size_t)arow * 32 + g16 * 8;
    float4 f0 = *(const float4*)xp;
    float4 f1 = *(const float4*)(xp + 4);
    bf16x8 ahi, alo;
    cvt_frag(f0, f1, ahi, alo);
    // GEMM1 -> redistribute pre-activation
#pragma unroll
    for (int jt = 0; jt < 4; jt++) {
        f32x4 a = {0.f, 0.f, 0.f, 0.f};
        a = mm3(ahi, alo, pk_in, jt, lane, a);
        float bias = b[jt * 16 + c16];
        if (g16 == 0) {
#pragma unroll
            for (int r = 0; r < 4; r++)
                ldsX[r * 64 + jt * 16 + c16] = a[r] + bias;
        }
    }
    __syncthreads();
    // epilogue: lane = node g16, channels jj*16+c16
    float gv[4];
    float ssum = 0.f;
#pragma unroll
    for (int jj = 0; jj < 4; jj++) {
        gv[jj] = gelu_f(ldsX[g16 * 64 + jj * 16 + c16]);
        ssum += gv[jj];
    }
    float mu = sum16(ssum) * (1.0f / 64.0f);
    float vs = 0.f;
#pragma unroll
    for (int jj = 0; jj < 4; jj++) {
        float d = gv[jj] - mu;
        vs += d * d;
    }
    float var = sum16(vs) * (1.0f / 64.0f);
    float rs = rsqrtf(var + 1e-5f);
#pragma unroll
    for (int jj = 0; jj < 4; jj++) {
        int ch = jj * 16 + c16;
        float hn = (gv[jj] - mu) * rs * g[ch] + be[ch];
        ldsH[g16 * 64 + ch] = hn;
    }
    __syncthreads();
    // vector h store
    {
        int row = g16, ck = c16;
        if (nb + row < n)
            *(float4*)(h + (size_t)(nb + row) * 64 + ck * 4) =
                *(const float4*)&ldsH[row * 64 + ck * 4];
    }
    qkv_gemm_store(ldsH, &ldsQf[0][0], pk_qkv, bn, q, kvout, nb, n, lane, g16, c16);
}

// ---------------- attention: qwe hoisted, no-max softmax, 8 edges/iter -------
__global__ __launch_bounds__(256) void k_attn(
    const __half* __restrict__ q, const __half* __restrict__ kv,
    const int* __restrict__ row, const int2* __restrict__ ep,
    const float* __restrict__ We, float* __restrict__ out, int n) {
    int lane = threadIdx.x & 63;
    int node = blockIdx.x * 4 + (threadIdx.x >> 6);
    if (node >= n) return;
    int g = lane >> 4;
    int c16 = lane & 15;
    int2 qb = *(const int2*)(q + (size_t)node * 64 + c16 * 4);
    float2 q01 = h2f2(qb.x), q23 = h2f2(qb.y);
    float4 wv = *(const float4*)(We + c16 * 4);
    // qwe per head (quad-group reduce), hoisted out of edge loop
    float qwe = sum4(q01.x * wv.x + q01.y * wv.y + q23.x * wv.z + q23.y * wv.w);
    int beg = row[node], end = row[node + 1];
    float den = 0.f, aes = 0.f;
    float4 acc = {0.f, 0.f, 0.f, 0.f};
    for (int pos = beg; pos < end; pos += 8) {
        int idx0 = pos + g, idx1 = pos + 4 + g;
        bool v0 = idx0 < end, v1 = idx1 < end;
        int2 pr0 = ep[v0 ? idx0 : beg];
        int2 pr1 = ep[v1 ? idx1 : beg];
        float a0 = __int_as_float(pr0.y), a1 = __int_as_float(pr1.y);
        int4 kb0 = *(const int4*)(kv + (size_t)pr0.x * 128 + c16 * 8);
        int4 kb1 = *(const int4*)(kv + (size_t)pr1.x * 128 + c16 * 8);
        {
            float2 k01 = h2f2(kb0.x), k23 = h2f2(kb0.y);
            float2 v01 = h2f2(kb0.z), v23 = h2f2(kb0.w);
            float p = q01.x * k01.x + q01.y * k01.y + q23.x * k23.x + q23.y * k23.y;
            p = sum4(p);
            float ex = v0 ? __expf(fminf(fmaf(a0, qwe, p) * 0.25f, 60.f)) : 0.f;
            den += ex;
            aes = fmaf(ex, a0, aes);
            acc.x = fmaf(ex, v01.x, acc.x);
            acc.y = fmaf(ex, v01.y, acc.y);
            acc.z = fmaf(ex, v23.x, acc.z);
            acc.w = fmaf(ex, v23.y, acc.w);
        }
        {
            float2 k01 = h2f2(kb1.x), k23 = h2f2(kb1.y);
            float2 v01 = h2f2(kb1.z), v23 = h2f2(kb1.w);
            float p = q01.x * k01.x + q01.y * k01.y + q23.x * k23.x + q23.y * k23.y;
            p = sum4(p);
            float ex = v1 ? __expf(fminf(fmaf(a1, qwe, p) * 0.25f, 60.f)) : 0.f;
            den += ex;
            aes = fmaf(ex, a1, aes);
            acc.x = fmaf(ex, v01.x, acc.x);
            acc.y = fmaf(ex, v01.y, acc.y);
            acc.z = fmaf(ex, v23.x, acc.z);
            acc.w = fmaf(ex, v23.y, acc.w);
        }
    }
#pragma unroll
    for (int mask = 16; mask <= 32; mask <<= 1) {
        den += __shfl_xor(den, mask, 64);
        aes += __shfl_xor(aes, mask, 64);
        acc.x += __shfl_xor(acc.x, mask, 64);
        acc.y += __shfl_xor(acc.y, mask, 64);
        acc.z += __shfl_xor(acc.z, mask, 64);
        acc.w += __shfl_xor(acc.w, mask, 64);
    }
    if (g == 0) {
        float inv = 1.0f / (den + 1e-16f);
        float4 o;
        o.x = fmaf(aes, wv.x, acc.x) * inv;
        o.y = fmaf(aes, wv.y, acc.y) * inv;
        o.z = fmaf(aes, wv.z, acc.z) * inv;
        o.w = fmaf(aes, wv.w, acc.w) * inv;
        *(float4*)(out + (size_t)node * 64 + c16 * 4) = o;
    }
}

// ---------------- node update (+qkv or pooling): 4 nodes per wave ------------
template <int DO_QKV>
__global__ __launch_bounds__(64) void k_node_qkv4(
    float* __restrict__ h, const float* __restrict__ o_in,
    const int4* __restrict__ pk_skip, const float* __restrict__ bs,
    const float* __restrict__ Wb, const float* __restrict__ lg,
    const float* __restrict__ lb, const int4* __restrict__ pk_qkv,
    const float* __restrict__ bn, __half* __restrict__ q,
    __half* __restrict__ kvout, const int* __restrict__ batch,
    float* __restrict__ gsum, unsigned int* __restrict__ gmaxu,
    float* __restrict__ cnt, int n) {
    __shared__ __align__(16) float ldsH[256];   // hnew epilogue layout [4][64]
    __shared__ __align__(16) float ldsX[256];   // xr redistribution
    __shared__ __align__(16) float ldsQf[4][100];
    int lane = threadIdx.x;
    int nb = blockIdx.x * 4;
    if (nb >= n) return;
    int g16 = lane >> 4, c16 = lane & 15;
    int myn = min(nb + g16, n - 1);
    int arow = min(nb + (c16 & 3), n - 1);
    // A-frag h rows (rows 4..15 duplicate)
    const float* hp = h + (size_t)arow * 64 + g16 * 8;
    float4 hf0 = *(const float4*)hp;
    float4 hf1 = *(const float4*)(hp + 4);
    float4 hf2 = *(const float4*)(hp + 32);
    float4 hf3 = *(const float4*)(hp + 36);
    // epilogue-layout direct loads (node g16, chs jj*16+c16)
    float ov[4], hold[4];
#pragma unroll
    for (int jj = 0; jj < 4; jj++) {
        ov[jj] = o_in[(size_t)myn * 64 + jj * 16 + c16];
        hold[jj] = h[(size_t)myn * 64 + jj * 16 + c16];
    }
    bf16x8 ahi[2], alo[2];
    cvt_frag(hf0, hf1, ahi[0], alo[0]);
    cvt_frag(hf2, hf3, ahi[1], alo[1]);
    // skip GEMM -> redistribute xr
#pragma unroll
    for (int jt = 0; jt < 4; jt++) {
        f32x4 a = {0.f, 0.f, 0.f, 0.f};
#pragma unroll
        for (int kt = 0; kt < 2; kt++)
            a = mm3(ahi[kt], alo[kt], pk_skip, jt * 2 + kt, lane, a);
        float bias = bs[jt * 16 + c16];
        if (g16 == 0) {
#pragma unroll
            for (int r = 0; r < 4; r++)
                ldsX[r * 64 + jt * 16 + c16] = a[r] + bias;
        }
    }
    __syncthreads();
    float xr[4], wb0[4], wb1[4], wb2[4], lgv[4], lbv[4];
#pragma unroll
    for (int jj = 0; jj < 4; jj++) {
        int ch = jj * 16 + c16;
        xr[jj] = ldsX[g16 * 64 + ch];
        wb0[jj] = Wb[ch]; wb1[jj] = Wb[64 + ch]; wb2[jj] = Wb[128 + ch];
        lgv[jj] = lg[ch]; lbv[jj] = lb[ch];
    }
    // beta gate + gelu + residual + LN (per node = 16-lane group)
    float cbs = 0.f;
#pragma unroll
    for (int jj = 0; jj < 4; jj++)
        cbs += ov[jj] * wb0[jj] + xr[jj] * wb1[jj] + (ov[jj] - xr[jj]) * wb2[jj];
    float cb = sum16(cbs);
    float beta = 1.0f / (1.0f + expf(-cb));
    float gvr[4], ssum = 0.f;
#pragma unroll
    for (int jj = 0; jj < 4; jj++) {
        float o2 = fmaf(beta, xr[jj] - ov[jj], ov[jj]);
        gvr[jj] = gelu_f(o2) + hold[jj];
        ssum += gvr[jj];
    }
    float mu = sum16(ssum) * (1.0f / 64.0f);
    float vs = 0.f;
#pragma unroll
    for (int jj = 0; jj < 4; jj++) {
        float d = gvr[jj] - mu;
        vs += d * d;
    }
    float var = sum16(vs) * (1.0f / 64.0f);
    float rs = rsqrtf(var + 1e-5f);
    float hnew[4];
#pragma unroll
    for (int jj = 0; jj < 4; jj++)
        hnew[jj] = (gvr[jj] - mu) * rs * lgv[jj] + lbv[jj];
    if (DO_QKV) {
#pragma unroll
        for (int jj = 0; jj < 4; jj++)
            ldsH[g16 * 64 + jj * 16 + c16] = hnew[jj];
        __syncthreads();
        {
            int row = g16, ck = c16;
            if (nb + row < n)
                *(float4*)(h + (size_t)(nb + row) * 64 + ck * 4) =
                    *(const float4*)&ldsH[row * 64 + ck * 4];
        }
        qkv_gemm_store(ldsH, &ldsQf[0][0], pk_qkv, bn, q, kvout, nb, n, lane, g16, c16);
    } else {
        // fused graph pooling (no h write)
        int gid = batch[myn];
        int g0 = batch[nb];
        bool allok = (nb + 3 < n);
        bool uni = allok && __all(gid == g0);
        if (uni) {
#pragma unroll
            for (int jj = 0; jj < 4; jj++) {
                float s = hnew[jj];
                float mx = hnew[jj];
                s += __shfl_xor(s, 16, 64);
                s += __shfl_xor(s, 32, 64);
                mx = fmaxf(mx, __shfl_xor(mx, 16, 64));
                mx = fmaxf(mx, __shfl_xor(mx, 32, 64));
                if (g16 == 0) {
                    int ch = jj * 16 + c16;
                    atomicAdd(&gsum[g0 * 64 + ch], s);
                    atomicMax(&gmaxu[g0 * 64 + ch], f2mono(mx));
                }
            }
            if (lane == 0) atomicAdd(&cnt[g0], 4.0f);
        } else {
            if (nb + g16 < n) {
#pragma unroll
                for (int jj = 0; jj < 4; jj++) {
                    int ch = jj * 16 + c16;
                    atomicAdd(&gsum[gid * 64 + ch], hnew[jj]);
                    atomicMax(&gmaxu[gid * 64 + ch], f2mono(hnew[jj]));
                }
                if (c16 == 0) atomicAdd(&cnt[gid], 1.0f);
            }
        }
    }
}

__global__ void k_final(const float* __restrict__ gsum,
                        const unsigned int* __restrict__ gmax,
                        const float* __restrict__ cnt,
                        const float* __restrict__ W1, const float* __restrict__ b1,
                        const float* __restrict__ W2, const float* __restrict__ b2,
                        const float* __restrict__ W3, const float* __restrict__ b3,
                        float* __restrict__ out) {
    int g = blockIdx.x;
    int lane = threadIdx.x;
    __shared__ float rep[128];
    __shared__ float t1[64];
    __shared__ float t2[32];
    float c = fmaxf(cnt[g], 1.0f);
    rep[lane] = gsum[g * 64 + lane] / c;
    rep[64 + lane] = mono2f(gmax[g * 64 + lane]);
    __syncthreads();
    float a = b1[lane];
#pragma unroll 8
    for (int i = 0; i < 128; i++) a = fmaf(rep[i], W1[i * 64 + lane], a);
    t1[lane] = gelu_f(a);
    __syncthreads();
    if (lane < 32) {
        float a2 = b2[lane];
#pragma unroll 8
        for (int i = 0; i < 64; i++) a2 = fmaf(t1[i], W2[i * 32 + lane], a2);
        t2[lane] = gelu_f(a2);
    }
    __syncthreads();
    if (lane < 32) {
        float p = t2[lane] * W3[lane];
#pragma unroll
        for (int o = 16; o > 0; o >>= 1) p += __shfl_xor(p, o, 64);
        if (lane == 0) out[g] = p + b3[0];
    }
}

extern "C" void kernel_launch(void* const* d_in, const int* in_sizes, int n_in,
                              void* d_out, int out_size, void* d_ws,
                              size_t ws_size, hipStream_t stream) {
    const float* x      = (const float*)d_in[0];
    const int*   eidx   = (const int*)d_in[1];
    const float* ea     = (const float*)d_in[2];
    const int*   batch  = (const int*)d_in[3];
    const float* in_W   = (const float*)d_in[4];
    const float* in_b   = (const float*)d_in[5];
    const float* in_lng = (const float*)d_in[6];
    const float* in_lnb = (const float*)d_in[7];
    const float* W_qkv  = (const float*)d_in[8];
    const float* b_qkv  = (const float*)d_in[9];
    const float* W_edge = (const float*)d_in[10];
    const float* W_skip = (const float*)d_in[11];
    const float* b_skip = (const float*)d_in[12];
    const float* W_beta = (const float*)d_in[13];
    const float* ln_g   = (const float*)d_in[14];
    const float* ln_b   = (const float*)d_in[15];
    const float* r1_W   = (const float*)d_in[16];
    const float* r1_b   = (const float*)d_in[17];
    const float* r2_W   = (const float*)d_in[18];
    const float* r2_b   = (const float*)d_in[19];
    const float* r3_W   = (const float*)d_in[20];
    const float* r3_b   = (const float*)d_in[21];

    int n = in_sizes[0] / 32;
    int E = in_sizes[2];
    const int* src = eidx;
    const int* dst = eidx + E;

    char* ws = (char*)d_ws;
    size_t off = 0;
    auto alloc = [&](size_t bytes) -> void* {
        void* p = ws + off;
        off = (off + bytes + 255) & ~(size_t)255;
        return p;
    };
    float* h    = (float*)alloc((size_t)n * 64 * 4);
    __half* qh  = (__half*)alloc((size_t)n * 64 * 2);
    __half* kvh = (__half*)alloc((size_t)n * 128 * 2);
    float* oacc = (float*)alloc((size_t)n * 64 * 4);
    int* deg    = (int*)alloc((size_t)n * 4);
    int* excl   = (int*)alloc((size_t)n * 4);
    int* bsum   = (int*)alloc(512 * 4);
    int* row    = (int*)alloc((size_t)(n + 1) * 4);
    int* cursor = (int*)alloc((size_t)n * 4);
    int* gcurb  = (int*)alloc(NBMAX * 4);
    int2* mid   = (int2*)alloc((size_t)E * 8);
    int2* ep    = (int2*)alloc((size_t)E * 8);
    int4* pk_in   = (int4*)alloc(4 * 128 * 16);
    int4* pk_skip = (int4*)alloc(3 * 8 * 128 * 16);
    int4* pk_qkv  = (int4*)alloc((size_t)3 * 24 * 128 * 16);
    float* gsum = (float*)alloc((NGRAPH * 64 * 2 + NGRAPH) * 4);
    unsigned int* gmaxu = (unsigned int*)(gsum + NGRAPH * 64);
    float* cnt  = gsum + NGRAPH * 128;

    int nb4 = (n + 3) / 4;
    int nbs = (n + 255) / 256;
    int ebs = (E + 255) / 256;
    int nbkt = (n + NPB - 1) >> 10;

    k_cvt<<<25, 256, 0, stream>>>(in_W, W_skip, W_qkv, pk_in, pk_skip, pk_qkv);
    hipMemsetAsync(deg, 0, (size_t)n * 4, stream);
    hipMemsetAsync(gsum, 0, (NGRAPH * 64 * 2 + NGRAPH) * 4, stream);
    k_hist<<<ebs, 256, 0, stream>>>(dst, deg, E);
    k_scan1<<<nbs, 256, 0, stream>>>(deg, excl, bsum, n);
    k_scan2<<<1, 512, 0, stream>>>(bsum, nbs);
    k_scan3<<<nbs, 256, 0, stream>>>(excl, bsum, row, cursor, gcurb, n, E);
    k_bucket<<<(E + 4095) / 4096, 256, 0, stream>>>(src, dst, ea, gcurb, mid, E, nbkt);
    k_local<<<dim3(nbkt, 4), 256, 0, stream>>>(row, cursor, mid, ep, n);

    k_in_qkv4<<<nb4, 64, 0, stream>>>(x, pk_in, in_b, in_lng, in_lnb,
                                      pk_qkv, b_qkv, h, qh, kvh, n);

    for (int l = 0; l < LAYERS; l++) {
        k_attn<<<nb4, 256, 0, stream>>>(qh, kvh, row, ep, W_edge + l * 64, oacc, n);
        if (l + 1 < LAYERS) {
            k_node_qkv4<1><<<nb4, 64, 0, stream>>>(
                h, oacc, pk_skip + l * 1024, b_skip + l * 64,
                W_beta + l * 192, ln_g + l * 64, ln_b + l * 64,
                pk_qkv + (size_t)(l + 1) * 3072, b_qkv + (size_t)(l + 1) * 192,
                qh, kvh, nullptr, nullptr, nullptr, nullptr, n);
        } else {
            k_node_qkv4<0><<<nb4, 64, 0, stream>>>(
                h, oacc, pk_skip + l * 1024, b_skip + l * 64,
                W_beta + l * 192, ln_g + l * 64, ln_b + l * 64,
                nullptr, nullptr, nullptr, nullptr,
                batch, gsum, gmaxu, cnt, n);
        }
    }

    k_final<<<NGRAPH, 64, 0, stream>>>(gsum, gmaxu, cnt, r1_W, r1_b, r2_W, r2_b,
                                       r3_W, r3_b, (float*)d_out);
}

// Round 18
// 377.489 us; speedup vs baseline: 1.5578x; 1.5578x over previous
//
#include <hip/hip_runtime.h>
#include <hip/hip_fp16.h>
#include <math.h>
#include <float.h>

#define LAYERS 3
#define NGRAPH 128
#define NPB 1024          // nodes per bucket (shift 10)
#define NBMAX 256

typedef __attribute__((ext_vector_type(8))) short bf16x8;
typedef __attribute__((ext_vector_type(4))) float f32x4;

union bfr { int4 i; bf16x8 b; };

__device__ __forceinline__ float gelu_f(float x) {
    return 0.5f * x * (1.0f + erff(x * 0.70710678118654752440f));
}

template <int CTRL, int RMASK>
__device__ __forceinline__ float dpp_add(float x) {
    int t = __builtin_amdgcn_update_dpp(0, __float_as_int(x), CTRL, RMASK, 0xF, false);
    return x + __int_as_float(t);
}

// sum over each 16-lane group; result in all 16 lanes
__device__ __forceinline__ float sum16(float v) {
    v = dpp_add<0xB1, 0xF>(v);
    v = dpp_add<0x4E, 0xF>(v);
    v = dpp_add<0x141, 0xF>(v);
    v = dpp_add<0x140, 0xF>(v);
    return v;
}
// sum over each 4-lane quad
__device__ __forceinline__ float sum4(float v) {
    v = dpp_add<0xB1, 0xF>(v);
    v = dpp_add<0x4E, 0xF>(v);
    return v;
}

__device__ __forceinline__ unsigned int f2mono(float f) {
    unsigned int u = __float_as_uint(f);
    return (u & 0x80000000u) ? ~u : (u | 0x80000000u);
}
__device__ __forceinline__ float mono2f(unsigned int u) {
    return (u & 0x80000000u) ? __uint_as_float(u ^ 0x80000000u)
                             : __uint_as_float(~u);
}

__device__ __forceinline__ float2 h2f2(int bits) {
    __half2 h = *reinterpret_cast<__half2*>(&bits);
    return __half22float2(h);
}

__device__ __forceinline__ void cvt_frag(const float4& f0, const float4& f1,
                                         bf16x8& hi, bf16x8& lo) {
    float ff[8] = {f0.x, f0.y, f0.z, f0.w, f1.x, f1.y, f1.z, f1.w};
#pragma unroll
    for (int j = 0; j < 8; j++) {
        unsigned u = __float_as_uint(ff[j]);
        hi[j] = (short)(u >> 16);
        float hf = __uint_as_float(u & 0xFFFF0000u);
        lo[j] = (short)(__float_as_uint(ff[j] - hf) >> 16);
    }
}

__device__ __forceinline__ f32x4 mm3(const bf16x8& ahi, const bf16x8& alo,
                                     const int4* __restrict__ pk, int tile,
                                     int lane, f32x4 acc) {
    bfr bh, bl;
    bh.i = pk[tile * 128 + lane];
    bl.i = pk[tile * 128 + 64 + lane];
    acc = __builtin_amdgcn_mfma_f32_16x16x32_bf16(alo, bh.b, acc, 0, 0, 0);
    acc = __builtin_amdgcn_mfma_f32_16x16x32_bf16(ahi, bl.b, acc, 0, 0, 0);
    acc = __builtin_amdgcn_mfma_f32_16x16x32_bf16(ahi, bh.b, acc, 0, 0, 0);
    return acc;
}

// kv interleaved row: slot (d>>2)*8 + 0..3 = k dims, +4..7 = v dims
__device__ __forceinline__ int kv_idx(int m, int cc) {
    return (cc >> 2) * 8 + (m - 1) * 4 + (cc & 3);
}

// ---------------- weight packing (once per launch) ----------------
__global__ __launch_bounds__(256) void k_cvt(
    const float* __restrict__ in_W, const float* __restrict__ W_skip,
    const float* __restrict__ W_qkv, int4* __restrict__ pk_in,
    int4* __restrict__ pk_skip, int4* __restrict__ pk_qkv) {
    int w = (blockIdx.x * 256 + threadIdx.x) >> 6;
    if (w >= 100) return;
    int lane = threadIdx.x & 63;
    const float* src;
    int4* dst;
    int kt, jt, qkvmode = 0;
    if (w < 4) {
        kt = 0; jt = w;
        src = in_W;
        dst = pk_in + w * 128;
    } else {
        int l = (w - 4) >> 5, r = (w - 4) & 31;
        if (r < 8) {
            kt = r & 1; jt = r >> 1;
            src = W_skip + l * 4096;
            dst = pk_skip + (l * 8 + r) * 128;
        } else {
            int tq = r - 8;
            kt = tq & 1; jt = tq >> 1;
            src = W_qkv + l * 12288;
            dst = pk_qkv + (l * 24 + tq) * 128;
            qkvmode = 1;
        }
    }
    int c = jt * 16 + (lane & 15);
    int koff = kt * 32 + (lane >> 4) * 8;
    unsigned hi[8], lo[8];
#pragma unroll
    for (int j = 0; j < 8; j++) {
        int k = koff + j;
        float f = qkvmode ? src[(c >> 6) * 4096 + k * 64 + (c & 63)]
                          : src[k * 64 + c];
        unsigned u = __float_as_uint(f);
        hi[j] = u >> 16;
        float hf = __uint_as_float(u & 0xFFFF0000u);
        lo[j] = __float_as_uint(f - hf) >> 16;
    }
    int4 H, L;
    H.x = hi[0] | (hi[1] << 16); H.y = hi[2] | (hi[3] << 16);
    H.z = hi[4] | (hi[5] << 16); H.w = hi[6] | (hi[7] << 16);
    L.x = lo[0] | (lo[1] << 16); L.y = lo[2] | (lo[3] << 16);
    L.z = lo[4] | (lo[5] << 16); L.w = lo[6] | (lo[7] << 16);
    dst[lane] = H;
    dst[64 + lane] = L;
}

// ---------------- CSR build ----------------
__global__ __launch_bounds__(256) void k_hist(const int* __restrict__ dst,
                                              int* __restrict__ deg, int E) {
    int e = blockIdx.x * 256 + threadIdx.x;
    if (e < E) atomicAdd(&deg[dst[e]], 1);
}

__global__ __launch_bounds__(256) void k_scan1(const int* __restrict__ deg,
                                               int* __restrict__ excl,
                                               int* __restrict__ bsum, int n) {
    __shared__ int s[256];
    int t = threadIdx.x;
    int i = blockIdx.x * 256 + t;
    int v = (i < n) ? deg[i] : 0;
    s[t] = v;
    __syncthreads();
    for (int off = 1; off < 256; off <<= 1) {
        int a = (t >= off) ? s[t - off] : 0;
        __syncthreads();
        s[t] += a;
        __syncthreads();
    }
    if (i < n) excl[i] = s[t] - v;
    if (t == 255) bsum[blockIdx.x] = s[255];
}

__global__ __launch_bounds__(512) void k_scan2(int* __restrict__ bsum, int nb) {
    __shared__ int s[512];
    int t = threadIdx.x;
    int v = (t < nb) ? bsum[t] : 0;
    s[t] = v;
    __syncthreads();
    for (int off = 1; off < 512; off <<= 1) {
        int a = (t >= off) ? s[t - off] : 0;
        __syncthreads();
        s[t] += a;
        __syncthreads();
    }
    if (t < nb) bsum[t] = s[t] - v;
}

__global__ __launch_bounds__(256) void k_scan3(const int* __restrict__ excl,
                                               const int* __restrict__ bsum,
                                               int* __restrict__ row,
                                               int* __restrict__ cursor,
                                               int* __restrict__ gcurb,
                                               int n, int E) {
    int i = blockIdx.x * 256 + threadIdx.x;
    if (i < n) {
        int r = excl[i] + bsum[blockIdx.x];
        row[i] = r;
        cursor[i] = r;
        if ((i & (NPB - 1)) == 0) gcurb[i >> 10] = r;
    }
    if (blockIdx.x == 0 && threadIdx.x == 0) row[n] = E;
}

// pass A: bin edges into node-range buckets; chunked writes.
__global__ __launch_bounds__(256) void k_bucket(
    const int* __restrict__ src, const int* __restrict__ dst,
    const float* __restrict__ ea, int* __restrict__ gcurb,
    int2* __restrict__ mid, int E, int nbkt) {
    __shared__ int cnt[NBMAX], base_[NBMAX];
    int tile = blockIdx.x * 4096;
    for (int i = threadIdx.x; i < nbkt; i += 256) cnt[i] = 0;
    __syncthreads();
    int d[16];
#pragma unroll
    for (int j = 0; j < 16; j++) {
        int e = tile + j * 256 + threadIdx.x;
        d[j] = -1;
        if (e < E) {
            d[j] = dst[e];
            atomicAdd(&cnt[d[j] >> 10], 1);
        }
    }
    __syncthreads();
    for (int i = threadIdx.x; i < nbkt; i += 256) {
        base_[i] = atomicAdd(&gcurb[i], cnt[i]);
        cnt[i] = 0;
    }
    __syncthreads();
#pragma unroll
    for (int j = 0; j < 16; j++) {
        int e = tile + j * 256 + threadIdx.x;
        if (e < E) {
            int b = d[j] >> 10;
            int p = base_[b] + atomicAdd(&cnt[b], 1);
            mid[p] = make_int2(src[e] | ((d[j] & (NPB - 1)) << 20),
                               __float_as_int(ea[e]));
        }
    }
}

// pass B: within-bucket permute to exact per-node CSR positions (L2-local)
__global__ __launch_bounds__(256) void k_local(
    const int* __restrict__ row, int* __restrict__ cursor,
    const int2* __restrict__ mid, int2* __restrict__ ep, int n) {
    int b = blockIdx.x;
    int n0 = b << 10;
    int n1 = min(n, n0 + NPB);
    int ebeg = row[n0], eend = row[n1];
    for (int e = ebeg + blockIdx.y * 256 + threadIdx.x; e < eend;
         e += 256 * gridDim.y) {
        int2 m = mid[e];
        int dn = n0 + ((m.x >> 20) & (NPB - 1));
        int p = atomicAdd(&cursor[dn], 1);
        ep[p] = make_int2(m.x & 0xFFFFF, m.y);
    }
}

// ---------------- fused input + layer-0 qkv (MFMA) ----------------
__global__ __launch_bounds__(256) void k_in_qkv(
    const float* __restrict__ x, const int4* __restrict__ pk_in,
    const float* __restrict__ b, const float* __restrict__ g,
    const float* __restrict__ be, const int4* __restrict__ pk_qkv,
    const float* __restrict__ bn, float* __restrict__ h,
    __half* __restrict__ q, __half* __restrict__ kvout, int n) {
    __shared__ float lds[4][1088];
    int lane = threadIdx.x & 63, wid = threadIdx.x >> 6;
    int nb = (blockIdx.x * 4 + wid) * 16;
    if (nb >= n) return;
    int g16 = lane >> 4, c16 = lane & 15;
    int arow = min(nb + c16, n - 1);
    const float* xp = x + (size_t)arow * 32 + g16 * 8;
    float4 f0 = *(const float4*)xp;
    float4 f1 = *(const float4*)(xp + 4);
    bf16x8 ahi, alo;
    cvt_frag(f0, f1, ahi, alo);
    float gv[4][4];
#pragma unroll
    for (int jt = 0; jt < 4; jt++) {
        f32x4 a = {0.f, 0.f, 0.f, 0.f};
        a = mm3(ahi, alo, pk_in, jt, lane, a);
        float bb = b[jt * 16 + c16];
#pragma unroll
        for (int r = 0; r < 4; r++) gv[jt][r] = gelu_f(a[r] + bb);
    }
    float gl[4], bel[4];
#pragma unroll
    for (int jt = 0; jt < 4; jt++) {
        gl[jt] = g[jt * 16 + c16];
        bel[jt] = be[jt * 16 + c16];
    }
    float hreg[4][4];
#pragma unroll
    for (int r = 0; r < 4; r++) {
        float s = gv[0][r] + gv[1][r] + gv[2][r] + gv[3][r];
        float mu = sum16(s) * (1.0f / 64.0f);
        float vs = 0.f;
#pragma unroll
        for (int jt = 0; jt < 4; jt++) {
            float d = gv[jt][r] - mu;
            vs += d * d;
        }
        float var = sum16(vs) * (1.0f / 64.0f);
        float rs = rsqrtf(var + 1e-5f);
#pragma unroll
        for (int jt = 0; jt < 4; jt++)
            hreg[jt][r] = (gv[jt][r] - mu) * rs * gl[jt] + bel[jt];
    }
#pragma unroll
    for (int jt = 0; jt < 4; jt++)
#pragma unroll
        for (int r = 0; r < 4; r++) {
            int nd = nb + g16 * 4 + r;
            if (nd < n) h[(size_t)nd * 64 + jt * 16 + c16] = hreg[jt][r];
            lds[wid][(g16 * 4 + r) * 68 + jt * 16 + c16] = hreg[jt][r];
        }
    bf16x8 qahi[2], qalo[2];
#pragma unroll
    for (int kt = 0; kt < 2; kt++) {
        const float* lp = &lds[wid][c16 * 68 + kt * 32 + g16 * 8];
        float4 t0 = *(const float4*)lp;
        float4 t1 = *(const float4*)(lp + 4);
        cvt_frag(t0, t1, qahi[kt], qalo[kt]);
    }
#pragma unroll
    for (int jt = 0; jt < 12; jt++) {
        f32x4 a = {0.f, 0.f, 0.f, 0.f};
#pragma unroll
        for (int kt = 0; kt < 2; kt++) a = mm3(qahi[kt], qalo[kt], pk_qkv, jt * 2 + kt, lane, a);
        int c = jt * 16 + c16;
        float bias = bn[c];
        int m = c >> 6, cc = c & 63;
#pragma unroll
        for (int r = 0; r < 4; r++) {
            int nd = nb + g16 * 4 + r;
            if (nd < n) {
                float val = a[r] + bias;
                if (m == 0) q[(size_t)nd * 64 + cc] = __float2half(val);
                else kvout[(size_t)nd * 128 + kv_idx(m, cc)] = __float2half(val);
            }
        }
    }
}

// ---------------- attention: qwe hoisted, no-max softmax, 8 edges/iter -------
__global__ __launch_bounds__(256) void k_attn(
    const __half* __restrict__ q, const __half* __restrict__ kv,
    const int* __restrict__ row, const int2* __restrict__ ep,
    const float* __restrict__ We, float* __restrict__ out, int n) {
    int lane = threadIdx.x & 63;
    int node = blockIdx.x * 4 + (threadIdx.x >> 6);
    if (node >= n) return;
    int g = lane >> 4;
    int c16 = lane & 15;
    int2 qb = *(const int2*)(q + (size_t)node * 64 + c16 * 4);
    float2 q01 = h2f2(qb.x), q23 = h2f2(qb.y);
    float4 wv = *(const float4*)(We + c16 * 4);
    // qwe per head (quad reduce), hoisted out of edge loop
    float qwe = sum4(q01.x * wv.x + q01.y * wv.y + q23.x * wv.z + q23.y * wv.w);
    int beg = row[node], end = row[node + 1];
    float den = 0.f, aes = 0.f;
    float4 acc = {0.f, 0.f, 0.f, 0.f};
    for (int pos = beg; pos < end; pos += 8) {
        int idx0 = pos + g, idx1 = pos + 4 + g;
        bool v0 = idx0 < end, v1 = idx1 < end;
        int2 pr0 = ep[v0 ? idx0 : beg];
        int2 pr1 = ep[v1 ? idx1 : beg];
        float a0 = __int_as_float(pr0.y), a1 = __int_as_float(pr1.y);
        int4 kb0 = *(const int4*)(kv + (size_t)pr0.x * 128 + c16 * 8);
        int4 kb1 = *(const int4*)(kv + (size_t)pr1.x * 128 + c16 * 8);
        {
            float2 k01 = h2f2(kb0.x), k23 = h2f2(kb0.y);
            float2 v01 = h2f2(kb0.z), v23 = h2f2(kb0.w);
            float p = q01.x * k01.x + q01.y * k01.y + q23.x * k23.x + q23.y * k23.y;
            p = sum4(p);
            float ex = v0 ? __expf(fminf(fmaf(a0, qwe, p) * 0.25f, 60.f)) : 0.f;
            den += ex;
            aes = fmaf(ex, a0, aes);
            acc.x = fmaf(ex, v01.x, acc.x);
            acc.y = fmaf(ex, v01.y, acc.y);
            acc.z = fmaf(ex, v23.x, acc.z);
            acc.w = fmaf(ex, v23.y, acc.w);
        }
        {
            float2 k01 = h2f2(kb1.x), k23 = h2f2(kb1.y);
            float2 v01 = h2f2(kb1.z), v23 = h2f2(kb1.w);
            float p = q01.x * k01.x + q01.y * k01.y + q23.x * k23.x + q23.y * k23.y;
            p = sum4(p);
            float ex = v1 ? __expf(fminf(fmaf(a1, qwe, p) * 0.25f, 60.f)) : 0.f;
            den += ex;
            aes = fmaf(ex, a1, aes);
            acc.x = fmaf(ex, v01.x, acc.x);
            acc.y = fmaf(ex, v01.y, acc.y);
            acc.z = fmaf(ex, v23.x, acc.z);
            acc.w = fmaf(ex, v23.y, acc.w);
        }
    }
#pragma unroll
    for (int mask = 16; mask <= 32; mask <<= 1) {
        den += __shfl_xor(den, mask, 64);
        aes += __shfl_xor(aes, mask, 64);
        acc.x += __shfl_xor(acc.x, mask, 64);
        acc.y += __shfl_xor(acc.y, mask, 64);
        acc.z += __shfl_xor(acc.z, mask, 64);
        acc.w += __shfl_xor(acc.w, mask, 64);
    }
    if (g == 0) {
        float inv = 1.0f / (den + 1e-16f);
        float4 o;
        o.x = fmaf(aes, wv.x, acc.x) * inv;
        o.y = fmaf(aes, wv.y, acc.y) * inv;
        o.z = fmaf(aes, wv.z, acc.z) * inv;
        o.w = fmaf(aes, wv.w, acc.w) * inv;
        *(float4*)(out + (size_t)node * 64 + c16 * 4) = o;
    }
}

// ---------------- fused node update + next-layer qkv OR final pooling --------
template <int DO_QKV>
__global__ __launch_bounds__(256) void k_node_qkv(
    float* __restrict__ h, const float* __restrict__ o_in,
    const int4* __restrict__ pk_skip, const float* __restrict__ bs,
    const float* __restrict__ Wb, const float* __restrict__ lg,
    const float* __restrict__ lb, const int4* __restrict__ pk_qkv,
    const float* __restrict__ bn, __half* __restrict__ q,
    __half* __restrict__ kvout, const int* __restrict__ batch,
    float* __restrict__ gsum, unsigned int* __restrict__ gmaxu,
    float* __restrict__ cnt, int n) {
    __shared__ float lds[4][DO_QKV ? 1088 : 4];
    int lane = threadIdx.x & 63, wid = threadIdx.x >> 6;
    int nb = (blockIdx.x * 4 + wid) * 16;
    if (nb >= n) return;
    int g16 = lane >> 4, c16 = lane & 15;
    bf16x8 ahi[2], alo[2];
    int arow = min(nb + c16, n - 1);
#pragma unroll
    for (int kt = 0; kt < 2; kt++) {
        const float* hp = h + (size_t)arow * 64 + kt * 32 + g16 * 8;
        float4 f0 = *(const float4*)hp;
        float4 f1 = *(const float4*)(hp + 4);
        cvt_frag(f0, f1, ahi[kt], alo[kt]);
    }
    float xr[4][4];
#pragma unroll
    for (int jt = 0; jt < 4; jt++) {
        f32x4 a = {0.f, 0.f, 0.f, 0.f};
#pragma unroll
        for (int kt = 0; kt < 2; kt++) a = mm3(ahi[kt], alo[kt], pk_skip, jt * 2 + kt, lane, a);
        float bias = bs[jt * 16 + c16];
#pragma unroll
        for (int r = 0; r < 4; r++) xr[jt][r] = a[r] + bias;
    }
    float ov[4][4], hold[4][4];
#pragma unroll
    for (int jt = 0; jt < 4; jt++)
#pragma unroll
        for (int r = 0; r < 4; r++) {
            int nd = min(nb + g16 * 4 + r, n - 1);
            ov[jt][r] = o_in[(size_t)nd * 64 + jt * 16 + c16];
            hold[jt][r] = h[(size_t)nd * 64 + jt * 16 + c16];
        }
    float wb0[4], wb1[4], wb2[4], lgv[4], lbv[4];
#pragma unroll
    for (int jt = 0; jt < 4; jt++) {
        int c = jt * 16 + c16;
        wb0[jt] = Wb[c]; wb1[jt] = Wb[64 + c]; wb2[jt] = Wb[128 + c];
        lgv[jt] = lg[c]; lbv[jt] = lb[c];
    }
    float hnew[4][4];
#pragma unroll
    for (int r = 0; r < 4; r++) {
        float cbs = 0.f;
#pragma unroll
        for (int jt = 0; jt < 4; jt++)
            cbs += ov[jt][r] * wb0[jt] + xr[jt][r] * wb1[jt] +
                   (ov[jt][r] - xr[jt][r]) * wb2[jt];
        float cb = sum16(cbs);
        float beta = 1.0f / (1.0f + expf(-cb));
        float gvr[4], s = 0.f;
#pragma unroll
        for (int jt = 0; jt < 4; jt++) {
            float o2 = fmaf(beta, xr[jt][r] - ov[jt][r], ov[jt][r]);
            gvr[jt] = gelu_f(o2) + hold[jt][r];
            s += gvr[jt];
        }
        float mu = sum16(s) * (1.0f / 64.0f);
        float vs = 0.f;
#pragma unroll
        for (int jt = 0; jt < 4; jt++) {
            float d = gvr[jt] - mu;
            vs += d * d;
        }
        float var = sum16(vs) * (1.0f / 64.0f);
        float rs = rsqrtf(var + 1e-5f);
#pragma unroll
        for (int jt = 0; jt < 4; jt++)
            hnew[jt][r] = (gvr[jt] - mu) * rs * lgv[jt] + lbv[jt];
    }
    if (DO_QKV) {
#pragma unroll
        for (int jt = 0; jt < 4; jt++)
#pragma unroll
            for (int r = 0; r < 4; r++) {
                int nd = nb + g16 * 4 + r;
                if (nd < n) h[(size_t)nd * 64 + jt * 16 + c16] = hnew[jt][r];
                lds[wid][(g16 * 4 + r) * 68 + jt * 16 + c16] = hnew[jt][r];
            }
        bf16x8 qahi[2], qalo[2];
#pragma unroll
        for (int kt = 0; kt < 2; kt++) {
            const float* lp = &lds[wid][c16 * 68 + kt * 32 + g16 * 8];
            float4 t0 = *(const float4*)lp;
            float4 t1 = *(const float4*)(lp + 4);
            cvt_frag(t0, t1, qahi[kt], qalo[kt]);
        }
#pragma unroll
        for (int jt = 0; jt < 12; jt++) {
            f32x4 a = {0.f, 0.f, 0.f, 0.f};
#pragma unroll
            for (int kt = 0; kt < 2; kt++) a = mm3(qahi[kt], qalo[kt], pk_qkv, jt * 2 + kt, lane, a);
            int c = jt * 16 + c16;
            float bias = bn[c];
            int m = c >> 6, cc = c & 63;
#pragma unroll
            for (int r = 0; r < 4; r++) {
                int nd = nb + g16 * 4 + r;
                if (nd < n) {
                    float val = a[r] + bias;
                    if (m == 0) q[(size_t)nd * 64 + cc] = __float2half(val);
                    else kvout[(size_t)nd * 128 + kv_idx(m, cc)] = __float2half(val);
                }
            }
        }
    } else {
        // fused graph pooling: no h write, accumulate rep directly
        int gid[4];
        int g0 = batch[nb];
        bool ok = (nb + 15 < n);
#pragma unroll
        for (int r = 0; r < 4; r++)
            gid[r] = batch[min(nb + g16 * 4 + r, n - 1)];
        bool uni = ok && __all(gid[0] == g0 && gid[1] == g0 &&
                               gid[2] == g0 && gid[3] == g0);
        if (uni) {
            float s[4], mx[4];
#pragma unroll
            for (int jt = 0; jt < 4; jt++) {
                s[jt] = hnew[jt][0] + hnew[jt][1] + hnew[jt][2] + hnew[jt][3];
                mx[jt] = fmaxf(fmaxf(hnew[jt][0], hnew[jt][1]),
                               fmaxf(hnew[jt][2], hnew[jt][3]));
            }
#pragma unroll
            for (int mask = 16; mask <= 32; mask <<= 1) {
#pragma unroll
                for (int jt = 0; jt < 4; jt++) {
                    s[jt] += __shfl_xor(s[jt], mask, 64);
                    mx[jt] = fmaxf(mx[jt], __shfl_xor(mx[jt], mask, 64));
                }
            }
            if (g16 == 0) {
#pragma unroll
                for (int jt = 0; jt < 4; jt++) {
                    int ch = jt * 16 + c16;
                    atomicAdd(&gsum[g0 * 64 + ch], s[jt]);
                    atomicMax(&gmaxu[g0 * 64 + ch], f2mono(mx[jt]));
                }
            }
            if (lane == 0) atomicAdd(&cnt[g0], 16.0f);
        } else {
#pragma unroll
            for (int r = 0; r < 4; r++) {
                int nd = nb + g16 * 4 + r;
                if (nd >= n) continue;
#pragma unroll
                for (int jt = 0; jt < 4; jt++) {
                    int ch = jt * 16 + c16;
                    atomicAdd(&gsum[gid[r] * 64 + ch], hnew[jt][r]);
                    atomicMax(&gmaxu[gid[r] * 64 + ch], f2mono(hnew[jt][r]));
                }
                if (c16 == 0) atomicAdd(&cnt[gid[r]], 1.0f);
            }
        }
    }
}

__global__ void k_final(const float* __restrict__ gsum,
                        const unsigned int* __restrict__ gmax,
                        const float* __restrict__ cnt,
                        const float* __restrict__ W1, const float* __restrict__ b1,
                        const float* __restrict__ W2, const float* __restrict__ b2,
                        const float* __restrict__ W3, const float* __restrict__ b3,
                        float* __restrict__ out) {
    int g = blockIdx.x;
    int lane = threadIdx.x;
    __shared__ float rep[128];
    __shared__ float t1[64];
    __shared__ float t2[32];
    float c = fmaxf(cnt[g], 1.0f);
    rep[lane] = gsum[g * 64 + lane] / c;
    rep[64 + lane] = mono2f(gmax[g * 64 + lane]);
    __syncthreads();
    float a = b1[lane];
#pragma unroll 8
    for (int i = 0; i < 128; i++) a = fmaf(rep[i], W1[i * 64 + lane], a);
    t1[lane] = gelu_f(a);
    __syncthreads();
    if (lane < 32) {
        float a2 = b2[lane];
#pragma unroll 8
        for (int i = 0; i < 64; i++) a2 = fmaf(t1[i], W2[i * 32 + lane], a2);
        t2[lane] = gelu_f(a2);
    }
    __syncthreads();
    if (lane < 32) {
        float p = t2[lane] * W3[lane];
#pragma unroll
        for (int o = 16; o > 0; o >>= 1) p += __shfl_xor(p, o, 64);
        if (lane == 0) out[g] = p + b3[0];
    }
}

extern "C" void kernel_launch(void* const* d_in, const int* in_sizes, int n_in,
                              void* d_out, int out_size, void* d_ws,
                              size_t ws_size, hipStream_t stream) {
    const float* x      = (const float*)d_in[0];
    const int*   eidx   = (const int*)d_in[1];
    const float* ea     = (const float*)d_in[2];
    const int*   batch  = (const int*)d_in[3];
    const float* in_W   = (const float*)d_in[4];
    const float* in_b   = (const float*)d_in[5];
    const float* in_lng = (const float*)d_in[6];
    const float* in_lnb = (const float*)d_in[7];
    const float* W_qkv  = (const float*)d_in[8];
    const float* b_qkv  = (const float*)d_in[9];
    const float* W_edge = (const float*)d_in[10];
    const float* W_skip = (const float*)d_in[11];
    const float* b_skip = (const float*)d_in[12];
    const float* W_beta = (const float*)d_in[13];
    const float* ln_g   = (const float*)d_in[14];
    const float* ln_b   = (const float*)d_in[15];
    const float* r1_W   = (const float*)d_in[16];
    const float* r1_b   = (const float*)d_in[17];
    const float* r2_W   = (const float*)d_in[18];
    const float* r2_b   = (const float*)d_in[19];
    const float* r3_W   = (const float*)d_in[20];
    const float* r3_b   = (const float*)d_in[21];

    int n = in_sizes[0] / 32;
    int E = in_sizes[2];
    const int* src = eidx;
    const int* dst = eidx + E;

    char* ws = (char*)d_ws;
    size_t off = 0;
    auto alloc = [&](size_t bytes) -> void* {
        void* p = ws + off;
        off = (off + bytes + 255) & ~(size_t)255;
        return p;
    };
    float* h    = (float*)alloc((size_t)n * 64 * 4);
    __half* qh  = (__half*)alloc((size_t)n * 64 * 2);
    __half* kvh = (__half*)alloc((size_t)n * 128 * 2);
    float* oacc = (float*)alloc((size_t)n * 64 * 4);
    int* deg    = (int*)alloc((size_t)n * 4);
    int* excl   = (int*)alloc((size_t)n * 4);
    int* bsum   = (int*)alloc(512 * 4);
    int* row    = (int*)alloc((size_t)(n + 1) * 4);
    int* cursor = (int*)alloc((size_t)n * 4);
    int* gcurb  = (int*)alloc(NBMAX * 4);
    int2* mid   = (int2*)alloc((size_t)E * 8);
    int2* ep    = (int2*)alloc((size_t)E * 8);
    int4* pk_in   = (int4*)alloc(4 * 128 * 16);
    int4* pk_skip = (int4*)alloc(3 * 8 * 128 * 16);
    int4* pk_qkv  = (int4*)alloc((size_t)3 * 24 * 128 * 16);
    float* gsum = (float*)alloc((NGRAPH * 64 * 2 + NGRAPH) * 4);
    unsigned int* gmaxu = (unsigned int*)(gsum + NGRAPH * 64);
    float* cnt  = gsum + NGRAPH * 128;

    int nb4 = (n + 3) / 4;
    int nb64 = (n + 63) / 64;
    int nbs = (n + 255) / 256;
    int ebs = (E + 255) / 256;
    int nbkt = (n + NPB - 1) >> 10;

    k_cvt<<<25, 256, 0, stream>>>(in_W, W_skip, W_qkv, pk_in, pk_skip, pk_qkv);
    hipMemsetAsync(deg, 0, (size_t)n * 4, stream);
    hipMemsetAsync(gsum, 0, (NGRAPH * 64 * 2 + NGRAPH) * 4, stream);
    k_hist<<<ebs, 256, 0, stream>>>(dst, deg, E);
    k_scan1<<<nbs, 256, 0, stream>>>(deg, excl, bsum, n);
    k_scan2<<<1, 512, 0, stream>>>(bsum, nbs);
    k_scan3<<<nbs, 256, 0, stream>>>(excl, bsum, row, cursor, gcurb, n, E);
    k_bucket<<<(E + 4095) / 4096, 256, 0, stream>>>(src, dst, ea, gcurb, mid, E, nbkt);
    k_local<<<dim3(nbkt, 4), 256, 0, stream>>>(row, cursor, mid, ep, n);

    k_in_qkv<<<nb64, 256, 0, stream>>>(x, pk_in, in_b, in_lng, in_lnb,
                                       pk_qkv, b_qkv, h, qh, kvh, n);

    for (int l = 0; l < LAYERS; l++) {
        k_attn<<<nb4, 256, 0, stream>>>(qh, kvh, row, ep, W_edge + l * 64, oacc, n);
        if (l + 1 < LAYERS) {
            k_node_qkv<1><<<nb64, 256, 0, stream>>>(
                h, oacc, pk_skip + l * 1024, b_skip + l * 64,
                W_beta + l * 192, ln_g + l * 64, ln_b + l * 64,
                pk_qkv + (size_t)(l + 1) * 3072, b_qkv + (size_t)(l + 1) * 192,
                qh, kvh, nullptr, nullptr, nullptr, nullptr, n);
        } else {
            k_node_qkv<0><<<nb64, 256, 0, stream>>>(
                h, oacc, pk_skip + l * 1024, b_skip + l * 64,
                W_beta + l * 192, ln_g + l * 64, ln_b + l * 64,
                nullptr, nullptr, nullptr, nullptr,
                batch, gsum, gmaxu, cnt, n);
        }
    }

    k_final<<<NGRAPH, 64, 0, stream>>>(gsum, gmaxu, cnt, r1_W, r1_b, r2_W, r2_b,
                                       r3_W, r3_b, (float*)d_out);
}

// Round 19
// 375.282 us; speedup vs baseline: 1.5670x; 1.0059x over previous
//
#include <hip/hip_runtime.h>
#include <hip/hip_fp16.h>
#include <math.h>
#include <float.h>

#define LAYERS 3
#define NGRAPH 128
#define NPB 1024          // nodes per bucket (shift 10)
#define NBMAX 256

typedef __attribute__((ext_vector_type(8))) short bf16x8;
typedef __attribute__((ext_vector_type(4))) float f32x4;
typedef _Float16 h2v __attribute__((ext_vector_type(2)));

union bfr { int4 i; bf16x8 b; };
union h2u { int i; h2v h; };

__device__ __forceinline__ float gelu_f(float x) {
    return 0.5f * x * (1.0f + erff(x * 0.70710678118654752440f));
}

template <int CTRL, int RMASK>
__device__ __forceinline__ float dpp_add(float x) {
    int t = __builtin_amdgcn_update_dpp(0, __float_as_int(x), CTRL, RMASK, 0xF, false);
    return x + __int_as_float(t);
}

// sum over each 16-lane group; result in all 16 lanes
__device__ __forceinline__ float sum16(float v) {
    v = dpp_add<0xB1, 0xF>(v);
    v = dpp_add<0x4E, 0xF>(v);
    v = dpp_add<0x141, 0xF>(v);
    v = dpp_add<0x140, 0xF>(v);
    return v;
}
// sum over each 4-lane quad
__device__ __forceinline__ float sum4(float v) {
    v = dpp_add<0xB1, 0xF>(v);
    v = dpp_add<0x4E, 0xF>(v);
    return v;
}

__device__ __forceinline__ unsigned int f2mono(float f) {
    unsigned int u = __float_as_uint(f);
    return (u & 0x80000000u) ? ~u : (u | 0x80000000u);
}
__device__ __forceinline__ float mono2f(unsigned int u) {
    return (u & 0x80000000u) ? __uint_as_float(u ^ 0x80000000u)
                             : __uint_as_float(~u);
}

__device__ __forceinline__ float2 h2f2(int bits) {
    __half2 h = *reinterpret_cast<__half2*>(&bits);
    return __half22float2(h);
}

__device__ __forceinline__ void cvt_frag(const float4& f0, const float4& f1,
                                         bf16x8& hi, bf16x8& lo) {
    float ff[8] = {f0.x, f0.y, f0.z, f0.w, f1.x, f1.y, f1.z, f1.w};
#pragma unroll
    for (int j = 0; j < 8; j++) {
        unsigned u = __float_as_uint(ff[j]);
        hi[j] = (short)(u >> 16);
        float hf = __uint_as_float(u & 0xFFFF0000u);
        lo[j] = (short)(__float_as_uint(ff[j] - hf) >> 16);
    }
}

__device__ __forceinline__ f32x4 mm3(const bf16x8& ahi, const bf16x8& alo,
                                     const int4* __restrict__ pk, int tile,
                                     int lane, f32x4 acc) {
    bfr bh, bl;
    bh.i = pk[tile * 128 + lane];
    bl.i = pk[tile * 128 + 64 + lane];
    acc = __builtin_amdgcn_mfma_f32_16x16x32_bf16(alo, bh.b, acc, 0, 0, 0);
    acc = __builtin_amdgcn_mfma_f32_16x16x32_bf16(ahi, bl.b, acc, 0, 0, 0);
    acc = __builtin_amdgcn_mfma_f32_16x16x32_bf16(ahi, bh.b, acc, 0, 0, 0);
    return acc;
}

// kv interleaved row: slot (d>>2)*8 + 0..3 = k dims, +4..7 = v dims
__device__ __forceinline__ int kv_idx(int m, int cc) {
    return (cc >> 2) * 8 + (m - 1) * 4 + (cc & 3);
}

// ---------------- weight packing (once per launch) ----------------
__global__ __launch_bounds__(256) void k_cvt(
    const float* __restrict__ in_W, const float* __restrict__ W_skip,
    const float* __restrict__ W_qkv, int4* __restrict__ pk_in,
    int4* __restrict__ pk_skip, int4* __restrict__ pk_qkv) {
    int w = (blockIdx.x * 256 + threadIdx.x) >> 6;
    if (w >= 100) return;
    int lane = threadIdx.x & 63;
    const float* src;
    int4* dst;
    int kt, jt, qkvmode = 0;
    if (w < 4) {
        kt = 0; jt = w;
        src = in_W;
        dst = pk_in + w * 128;
    } else {
        int l = (w - 4) >> 5, r = (w - 4) & 31;
        if (r < 8) {
            kt = r & 1; jt = r >> 1;
            src = W_skip + l * 4096;
            dst = pk_skip + (l * 8 + r) * 128;
        } else {
            int tq = r - 8;
            kt = tq & 1; jt = tq >> 1;
            src = W_qkv + l * 12288;
            dst = pk_qkv + (l * 24 + tq) * 128;
            qkvmode = 1;
        }
    }
    int c = jt * 16 + (lane & 15);
    int koff = kt * 32 + (lane >> 4) * 8;
    unsigned hi[8], lo[8];
#pragma unroll
    for (int j = 0; j < 8; j++) {
        int k = koff + j;
        float f = qkvmode ? src[(c >> 6) * 4096 + k * 64 + (c & 63)]
                          : src[k * 64 + c];
        unsigned u = __float_as_uint(f);
        hi[j] = u >> 16;
        float hf = __uint_as_float(u & 0xFFFF0000u);
        lo[j] = __float_as_uint(f - hf) >> 16;
    }
    int4 H, L;
    H.x = hi[0] | (hi[1] << 16); H.y = hi[2] | (hi[3] << 16);
    H.z = hi[4] | (hi[5] << 16); H.w = hi[6] | (hi[7] << 16);
    L.x = lo[0] | (lo[1] << 16); L.y = lo[2] | (lo[3] << 16);
    L.z = lo[4] | (lo[5] << 16); L.w = lo[6] | (lo[7] << 16);
    dst[lane] = H;
    dst[64 + lane] = L;
}

// ---------------- CSR build ----------------
__global__ __launch_bounds__(256) void k_hist(const int* __restrict__ dst,
                                              int* __restrict__ deg, int E) {
    int e = blockIdx.x * 256 + threadIdx.x;
    if (e < E) atomicAdd(&deg[dst[e]], 1);
}

__global__ __launch_bounds__(256) void k_scan1(const int* __restrict__ deg,
                                               int* __restrict__ excl,
                                               int* __restrict__ bsum, int n) {
    __shared__ int s[256];
    int t = threadIdx.x;
    int i = blockIdx.x * 256 + t;
    int v = (i < n) ? deg[i] : 0;
    s[t] = v;
    __syncthreads();
    for (int off = 1; off < 256; off <<= 1) {
        int a = (t >= off) ? s[t - off] : 0;
        __syncthreads();
        s[t] += a;
        __syncthreads();
    }
    if (i < n) excl[i] = s[t] - v;
    if (t == 255) bsum[blockIdx.x] = s[255];
}

__global__ __launch_bounds__(512) void k_scan2(int* __restrict__ bsum, int nb) {
    __shared__ int s[512];
    int t = threadIdx.x;
    int v = (t < nb) ? bsum[t] : 0;
    s[t] = v;
    __syncthreads();
    for (int off = 1; off < 512; off <<= 1) {
        int a = (t >= off) ? s[t - off] : 0;
        __syncthreads();
        s[t] += a;
        __syncthreads();
    }
    if (t < nb) bsum[t] = s[t] - v;
}

__global__ __launch_bounds__(256) void k_scan3(const int* __restrict__ excl,
                                               const int* __restrict__ bsum,
                                               int* __restrict__ row,
                                               int* __restrict__ cursor,
                                               int* __restrict__ gcurb,
                                               int n, int E) {
    int i = blockIdx.x * 256 + threadIdx.x;
    if (i < n) {
        int r = excl[i] + bsum[blockIdx.x];
        row[i] = r;
        cursor[i] = r;
        if ((i & (NPB - 1)) == 0) gcurb[i >> 10] = r;
    }
    if (blockIdx.x == 0 && threadIdx.x == 0) row[n] = E;
}

// pass A: bin edges into node-range buckets; chunked writes.
__global__ __launch_bounds__(256) void k_bucket(
    const int* __restrict__ src, const int* __restrict__ dst,
    const float* __restrict__ ea, int* __restrict__ gcurb,
    int2* __restrict__ mid, int E, int nbkt) {
    __shared__ int cnt[NBMAX], base_[NBMAX];
    int tile = blockIdx.x * 4096;
    for (int i = threadIdx.x; i < nbkt; i += 256) cnt[i] = 0;
    __syncthreads();
    int d[16];
#pragma unroll
    for (int j = 0; j < 16; j++) {
        int e = tile + j * 256 + threadIdx.x;
        d[j] = -1;
        if (e < E) {
            d[j] = dst[e];
            atomicAdd(&cnt[d[j] >> 10], 1);
        }
    }
    __syncthreads();
    for (int i = threadIdx.x; i < nbkt; i += 256) {
        base_[i] = atomicAdd(&gcurb[i], cnt[i]);
        cnt[i] = 0;
    }
    __syncthreads();
#pragma unroll
    for (int j = 0; j < 16; j++) {
        int e = tile + j * 256 + threadIdx.x;
        if (e < E) {
            int b = d[j] >> 10;
            int p = base_[b] + atomicAdd(&cnt[b], 1);
            mid[p] = make_int2(src[e] | ((d[j] & (NPB - 1)) << 20),
                               __float_as_int(ea[e]));
        }
    }
}

// pass B: within-bucket permute to exact per-node CSR positions (L2-local)
__global__ __launch_bounds__(256) void k_local(
    const int* __restrict__ row, int* __restrict__ cursor,
    const int2* __restrict__ mid, int2* __restrict__ ep, int n) {
    int b = blockIdx.x;
    int n0 = b << 10;
    int n1 = min(n, n0 + NPB);
    int ebeg = row[n0], eend = row[n1];
    for (int e = ebeg + blockIdx.y * 256 + threadIdx.x; e < eend;
         e += 256 * gridDim.y) {
        int2 m = mid[e];
        int dn = n0 + ((m.x >> 20) & (NPB - 1));
        int p = atomicAdd(&cursor[dn], 1);
        ep[p] = make_int2(m.x & 0xFFFFF, m.y);
    }
}

// ---------------- fused input + layer-0 qkv (MFMA) ----------------
__global__ __launch_bounds__(256) void k_in_qkv(
    const float* __restrict__ x, const int4* __restrict__ pk_in,
    const float* __restrict__ b, const float* __restrict__ g,
    const float* __restrict__ be, const int4* __restrict__ pk_qkv,
    const float* __restrict__ bn, float* __restrict__ h,
    __half* __restrict__ q, __half* __restrict__ kvout, int n) {
    __shared__ float lds[4][1088];
    int lane = threadIdx.x & 63, wid = threadIdx.x >> 6;
    int nb = (blockIdx.x * 4 + wid) * 16;
    if (nb >= n) return;
    int g16 = lane >> 4, c16 = lane & 15;
    int arow = min(nb + c16, n - 1);
    const float* xp = x + (size_t)arow * 32 + g16 * 8;
    float4 f0 = *(const float4*)xp;
    float4 f1 = *(const float4*)(xp + 4);
    bf16x8 ahi, alo;
    cvt_frag(f0, f1, ahi, alo);
    float gv[4][4];
#pragma unroll
    for (int jt = 0; jt < 4; jt++) {
        f32x4 a = {0.f, 0.f, 0.f, 0.f};
        a = mm3(ahi, alo, pk_in, jt, lane, a);
        float bb = b[jt * 16 + c16];
#pragma unroll
        for (int r = 0; r < 4; r++) gv[jt][r] = gelu_f(a[r] + bb);
    }
    float gl[4], bel[4];
#pragma unroll
    for (int jt = 0; jt < 4; jt++) {
        gl[jt] = g[jt * 16 + c16];
        bel[jt] = be[jt * 16 + c16];
    }
    float hreg[4][4];
#pragma unroll
    for (int r = 0; r < 4; r++) {
        float s = gv[0][r] + gv[1][r] + gv[2][r] + gv[3][r];
        float mu = sum16(s) * (1.0f / 64.0f);
        float vs = 0.f;
#pragma unroll
        for (int jt = 0; jt < 4; jt++) {
            float d = gv[jt][r] - mu;
            vs += d * d;
        }
        float var = sum16(vs) * (1.0f / 64.0f);
        float rs = rsqrtf(var + 1e-5f);
#pragma unroll
        for (int jt = 0; jt < 4; jt++)
            hreg[jt][r] = (gv[jt][r] - mu) * rs * gl[jt] + bel[jt];
    }
#pragma unroll
    for (int jt = 0; jt < 4; jt++)
#pragma unroll
        for (int r = 0; r < 4; r++) {
            int nd = nb + g16 * 4 + r;
            if (nd < n) h[(size_t)nd * 64 + jt * 16 + c16] = hreg[jt][r];
            lds[wid][(g16 * 4 + r) * 68 + jt * 16 + c16] = hreg[jt][r];
        }
    bf16x8 qahi[2], qalo[2];
#pragma unroll
    for (int kt = 0; kt < 2; kt++) {
        const float* lp = &lds[wid][c16 * 68 + kt * 32 + g16 * 8];
        float4 t0 = *(const float4*)lp;
        float4 t1 = *(const float4*)(lp + 4);
        cvt_frag(t0, t1, qahi[kt], qalo[kt]);
    }
#pragma unroll
    for (int jt = 0; jt < 12; jt++) {
        f32x4 a = {0.f, 0.f, 0.f, 0.f};
#pragma unroll
        for (int kt = 0; kt < 2; kt++) a = mm3(qahi[kt], qalo[kt], pk_qkv, jt * 2 + kt, lane, a);
        int c = jt * 16 + c16;
        float bias = bn[c];
        int m = c >> 6, cc = c & 63;
#pragma unroll
        for (int r = 0; r < 4; r++) {
            int nd = nb + g16 * 4 + r;
            if (nd < n) {
                float val = a[r] + bias;
                if (m == 0) q[(size_t)nd * 64 + cc] = __float2half(val);
                else kvout[(size_t)nd * 128 + kv_idx(m, cc)] = __float2half(val);
            }
        }
    }
}

// ---------------- attention: fdot2 dot, qwe hoisted, no-max softmax ----------
__global__ __launch_bounds__(256) void k_attn(
    const __half* __restrict__ q, const __half* __restrict__ kv,
    const int* __restrict__ row, const int2* __restrict__ ep,
    const float* __restrict__ We, float* __restrict__ out, int n) {
    int lane = threadIdx.x & 63;
    int node = blockIdx.x * 4 + (threadIdx.x >> 6);
    if (node >= n) return;
    int g = lane >> 4;
    int c16 = lane & 15;
    int2 qb = *(const int2*)(q + (size_t)node * 64 + c16 * 4);
    h2u qh01, qh23;
    qh01.i = qb.x;
    qh23.i = qb.y;
    float2 q01 = h2f2(qb.x), q23 = h2f2(qb.y);
    float4 wv = *(const float4*)(We + c16 * 4);
    // qwe per head (quad reduce), hoisted out of edge loop
    float qwe = sum4(q01.x * wv.x + q01.y * wv.y + q23.x * wv.z + q23.y * wv.w);
    int beg = row[node], end = row[node + 1];
    float den = 0.f, aes = 0.f;
    float4 acc = {0.f, 0.f, 0.f, 0.f};
    for (int pos = beg; pos < end; pos += 8) {
        int idx0 = pos + g, idx1 = pos + 4 + g;
        bool v0 = idx0 < end, v1 = idx1 < end;
        int2 pr0 = ep[v0 ? idx0 : beg];
        int2 pr1 = ep[v1 ? idx1 : beg];
        float a0 = __int_as_float(pr0.y), a1 = __int_as_float(pr1.y);
        int4 kb0 = *(const int4*)(kv + (size_t)pr0.x * 128 + c16 * 8);
        int4 kb1 = *(const int4*)(kv + (size_t)pr1.x * 128 + c16 * 8);
        {
            h2u k01, k23;
            k01.i = kb0.x;
            k23.i = kb0.y;
            float p = __builtin_amdgcn_fdot2(
                qh01.h, k01.h,
                __builtin_amdgcn_fdot2(qh23.h, k23.h, 0.f, false), false);
            p = sum4(p);
            float2 v01 = h2f2(kb0.z), v23 = h2f2(kb0.w);
            float ex = v0 ? __expf(fminf(fmaf(a0, qwe, p) * 0.25f, 60.f)) : 0.f;
            den += ex;
            aes = fmaf(ex, a0, aes);
            acc.x = fmaf(ex, v01.x, acc.x);
            acc.y = fmaf(ex, v01.y, acc.y);
            acc.z = fmaf(ex, v23.x, acc.z);
            acc.w = fmaf(ex, v23.y, acc.w);
        }
        {
            h2u k01, k23;
            k01.i = kb1.x;
            k23.i = kb1.y;
            float p = __builtin_amdgcn_fdot2(
                qh01.h, k01.h,
                __builtin_amdgcn_fdot2(qh23.h, k23.h, 0.f, false), false);
            p = sum4(p);
            float2 v01 = h2f2(kb1.z), v23 = h2f2(kb1.w);
            float ex = v1 ? __expf(fminf(fmaf(a1, qwe, p) * 0.25f, 60.f)) : 0.f;
            den += ex;
            aes = fmaf(ex, a1, aes);
            acc.x = fmaf(ex, v01.x, acc.x);
            acc.y = fmaf(ex, v01.y, acc.y);
            acc.z = fmaf(ex, v23.x, acc.z);
            acc.w = fmaf(ex, v23.y, acc.w);
        }
    }
#pragma unroll
    for (int mask = 16; mask <= 32; mask <<= 1) {
        den += __shfl_xor(den, mask, 64);
        aes += __shfl_xor(aes, mask, 64);
        acc.x += __shfl_xor(acc.x, mask, 64);
        acc.y += __shfl_xor(acc.y, mask, 64);
        acc.z += __shfl_xor(acc.z, mask, 64);
        acc.w += __shfl_xor(acc.w, mask, 64);
    }
    if (g == 0) {
        float inv = 1.0f / (den + 1e-16f);
        float4 o;
        o.x = fmaf(aes, wv.x, acc.x) * inv;
        o.y = fmaf(aes, wv.y, acc.y) * inv;
        o.z = fmaf(aes, wv.z, acc.z) * inv;
        o.w = fmaf(aes, wv.w, acc.w) * inv;
        *(float4*)(out + (size_t)node * 64 + c16 * 4) = o;
    }
}

// ---------------- fused node update + next-layer qkv OR final pooling --------
template <int DO_QKV>
__global__ __launch_bounds__(256) void k_node_qkv(
    float* __restrict__ h, const float* __restrict__ o_in,
    const int4* __restrict__ pk_skip, const float* __restrict__ bs,
    const float* __restrict__ Wb, const float* __restrict__ lg,
    const float* __restrict__ lb, const int4* __restrict__ pk_qkv,
    const float* __restrict__ bn, __half* __restrict__ q,
    __half* __restrict__ kvout, const int* __restrict__ batch,
    float* __restrict__ gsum, unsigned int* __restrict__ gmaxu,
    float* __restrict__ cnt, int n) {
    __shared__ float lds[4][DO_QKV ? 1088 : 4];
    int lane = threadIdx.x & 63, wid = threadIdx.x >> 6;
    int nb = (blockIdx.x * 4 + wid) * 16;
    if (nb >= n) return;
    int g16 = lane >> 4, c16 = lane & 15;
    bf16x8 ahi[2], alo[2];
    int arow = min(nb + c16, n - 1);
#pragma unroll
    for (int kt = 0; kt < 2; kt++) {
        const float* hp = h + (size_t)arow * 64 + kt * 32 + g16 * 8;
        float4 f0 = *(const float4*)hp;
        float4 f1 = *(const float4*)(hp + 4);
        cvt_frag(f0, f1, ahi[kt], alo[kt]);
    }
    float xr[4][4];
#pragma unroll
    for (int jt = 0; jt < 4; jt++) {
        f32x4 a = {0.f, 0.f, 0.f, 0.f};
#pragma unroll
        for (int kt = 0; kt < 2; kt++) a = mm3(ahi[kt], alo[kt], pk_skip, jt * 2 + kt, lane, a);
        float bias = bs[jt * 16 + c16];
#pragma unroll
        for (int r = 0; r < 4; r++) xr[jt][r] = a[r] + bias;
    }
    float ov[4][4], hold[4][4];
#pragma unroll
    for (int jt = 0; jt < 4; jt++)
#pragma unroll
        for (int r = 0; r < 4; r++) {
            int nd = min(nb + g16 * 4 + r, n - 1);
            ov[jt][r] = o_in[(size_t)nd * 64 + jt * 16 + c16];
            hold[jt][r] = h[(size_t)nd * 64 + jt * 16 + c16];
        }
    float wb0[4], wb1[4], wb2[4], lgv[4], lbv[4];
#pragma unroll
    for (int jt = 0; jt < 4; jt++) {
        int c = jt * 16 + c16;
        wb0[jt] = Wb[c]; wb1[jt] = Wb[64 + c]; wb2[jt] = Wb[128 + c];
        lgv[jt] = lg[c]; lbv[jt] = lb[c];
    }
    float hnew[4][4];
#pragma unroll
    for (int r = 0; r < 4; r++) {
        float cbs = 0.f;
#pragma unroll
        for (int jt = 0; jt < 4; jt++)
            cbs += ov[jt][r] * wb0[jt] + xr[jt][r] * wb1[jt] +
                   (ov[jt][r] - xr[jt][r]) * wb2[jt];
        float cb = sum16(cbs);
        float beta = 1.0f / (1.0f + expf(-cb));
        float gvr[4], s = 0.f;
#pragma unroll
        for (int jt = 0; jt < 4; jt++) {
            float o2 = fmaf(beta, xr[jt][r] - ov[jt][r], ov[jt][r]);
            gvr[jt] = gelu_f(o2) + hold[jt][r];
            s += gvr[jt];
        }
        float mu = sum16(s) * (1.0f / 64.0f);
        float vs = 0.f;
#pragma unroll
        for (int jt = 0; jt < 4; jt++) {
            float d = gvr[jt] - mu;
            vs += d * d;
        }
        float var = sum16(vs) * (1.0f / 64.0f);
        float rs = rsqrtf(var + 1e-5f);
#pragma unroll
        for (int jt = 0; jt < 4; jt++)
            hnew[jt][r] = (gvr[jt] - mu) * rs * lgv[jt] + lbv[jt];
    }
    if (DO_QKV) {
#pragma unroll
        for (int jt = 0; jt < 4; jt++)
#pragma unroll
            for (int r = 0; r < 4; r++) {
                int nd = nb + g16 * 4 + r;
                if (nd < n) h[(size_t)nd * 64 + jt * 16 + c16] = hnew[jt][r];
                lds[wid][(g16 * 4 + r) * 68 + jt * 16 + c16] = hnew[jt][r];
            }
        bf16x8 qahi[2], qalo[2];
#pragma unroll
        for (int kt = 0; kt < 2; kt++) {
            const float* lp = &lds[wid][c16 * 68 + kt * 32 + g16 * 8];
            float4 t0 = *(const float4*)lp;
            float4 t1 = *(const float4*)(lp + 4);
            cvt_frag(t0, t1, qahi[kt], qalo[kt]);
        }
#pragma unroll
        for (int jt = 0; jt < 12; jt++) {
            f32x4 a = {0.f, 0.f, 0.f, 0.f};
#pragma unroll
            for (int kt = 0; kt < 2; kt++) a = mm3(qahi[kt], qalo[kt], pk_qkv, jt * 2 + kt, lane, a);
            int c = jt * 16 + c16;
            float bias = bn[c];
            int m = c >> 6, cc = c & 63;
#pragma unroll
            for (int r = 0; r < 4; r++) {
                int nd = nb + g16 * 4 + r;
                if (nd < n) {
                    float val = a[r] + bias;
                    if (m == 0) q[(size_t)nd * 64 + cc] = __float2half(val);
                    else kvout[(size_t)nd * 128 + kv_idx(m, cc)] = __float2half(val);
                }
            }
        }
    } else {
        // fused graph pooling: no h write, accumulate rep directly
        int gid[4];
        int g0 = batch[nb];
        bool ok = (nb + 15 < n);
#pragma unroll
        for (int r = 0; r < 4; r++)
            gid[r] = batch[min(nb + g16 * 4 + r, n - 1)];
        bool uni = ok && __all(gid[0] == g0 && gid[1] == g0 &&
                               gid[2] == g0 && gid[3] == g0);
        if (uni) {
            float s[4], mx[4];
#pragma unroll
            for (int jt = 0; jt < 4; jt++) {
                s[jt] = hnew[jt][0] + hnew[jt][1] + hnew[jt][2] + hnew[jt][3];
                mx[jt] = fmaxf(fmaxf(hnew[jt][0], hnew[jt][1]),
                               fmaxf(hnew[jt][2], hnew[jt][3]));
            }
#pragma unroll
            for (int mask = 16; mask <= 32; mask <<= 1) {
#pragma unroll
                for (int jt = 0; jt < 4; jt++) {
                    s[jt] += __shfl_xor(s[jt], mask, 64);
                    mx[jt] = fmaxf(mx[jt], __shfl_xor(mx[jt], mask, 64));
                }
            }
            if (g16 == 0) {
#pragma unroll
                for (int jt = 0; jt < 4; jt++) {
                    int ch = jt * 16 + c16;
                    atomicAdd(&gsum[g0 * 64 + ch], s[jt]);
                    atomicMax(&gmaxu[g0 * 64 + ch], f2mono(mx[jt]));
                }
            }
            if (lane == 0) atomicAdd(&cnt[g0], 16.0f);
        } else {
#pragma unroll
            for (int r = 0; r < 4; r++) {
                int nd = nb + g16 * 4 + r;
                if (nd >= n) continue;
#pragma unroll
                for (int jt = 0; jt < 4; jt++) {
                    int ch = jt * 16 + c16;
                    atomicAdd(&gsum[gid[r] * 64 + ch], hnew[jt][r]);
                    atomicMax(&gmaxu[gid[r] * 64 + ch], f2mono(hnew[jt][r]));
                }
                if (c16 == 0) atomicAdd(&cnt[gid[r]], 1.0f);
            }
        }
    }
}

__global__ void k_final(const float* __restrict__ gsum,
                        const unsigned int* __restrict__ gmax,
                        const float* __restrict__ cnt,
                        const float* __restrict__ W1, const float* __restrict__ b1,
                        const float* __restrict__ W2, const float* __restrict__ b2,
                        const float* __restrict__ W3, const float* __restrict__ b3,
                        float* __restrict__ out) {
    int g = blockIdx.x;
    int lane = threadIdx.x;
    __shared__ float rep[128];
    __shared__ float t1[64];
    __shared__ float t2[32];
    float c = fmaxf(cnt[g], 1.0f);
    rep[lane] = gsum[g * 64 + lane] / c;
    rep[64 + lane] = mono2f(gmax[g * 64 + lane]);
    __syncthreads();
    float a = b1[lane];
#pragma unroll 8
    for (int i = 0; i < 128; i++) a = fmaf(rep[i], W1[i * 64 + lane], a);
    t1[lane] = gelu_f(a);
    __syncthreads();
    if (lane < 32) {
        float a2 = b2[lane];
#pragma unroll 8
        for (int i = 0; i < 64; i++) a2 = fmaf(t1[i], W2[i * 32 + lane], a2);
        t2[lane] = gelu_f(a2);
    }
    __syncthreads();
    if (lane < 32) {
        float p = t2[lane] * W3[lane];
#pragma unroll
        for (int o = 16; o > 0; o >>= 1) p += __shfl_xor(p, o, 64);
        if (lane == 0) out[g] = p + b3[0];
    }
}

extern "C" void kernel_launch(void* const* d_in, const int* in_sizes, int n_in,
                              void* d_out, int out_size, void* d_ws,
                              size_t ws_size, hipStream_t stream) {
    const float* x      = (const float*)d_in[0];
    const int*   eidx   = (const int*)d_in[1];
    const float* ea     = (const float*)d_in[2];
    const int*   batch  = (const int*)d_in[3];
    const float* in_W   = (const float*)d_in[4];
    const float* in_b   = (const float*)d_in[5];
    const float* in_lng = (const float*)d_in[6];
    const float* in_lnb = (const float*)d_in[7];
    const float* W_qkv  = (const float*)d_in[8];
    const float* b_qkv  = (const float*)d_in[9];
    const float* W_edge = (const float*)d_in[10];
    const float* W_skip = (const float*)d_in[11];
    const float* b_skip = (const float*)d_in[12];
    const float* W_beta = (const float*)d_in[13];
    const float* ln_g   = (const float*)d_in[14];
    const float* ln_b   = (const float*)d_in[15];
    const float* r1_W   = (const float*)d_in[16];
    const float* r1_b   = (const float*)d_in[17];
    const float* r2_W   = (const float*)d_in[18];
    const float* r2_b   = (const float*)d_in[19];
    const float* r3_W   = (const float*)d_in[20];
    const float* r3_b   = (const float*)d_in[21];

    int n = in_sizes[0] / 32;
    int E = in_sizes[2];
    const int* src = eidx;
    const int* dst = eidx + E;

    char* ws = (char*)d_ws;
    size_t off = 0;
    auto alloc = [&](size_t bytes) -> void* {
        void* p = ws + off;
        off = (off + bytes + 255) & ~(size_t)255;
        return p;
    };
    float* h    = (float*)alloc((size_t)n * 64 * 4);
    __half* qh  = (__half*)alloc((size_t)n * 64 * 2);
    __half* kvh = (__half*)alloc((size_t)n * 128 * 2);
    float* oacc = (float*)alloc((size_t)n * 64 * 4);
    int* deg    = (int*)alloc((size_t)n * 4);
    int* excl   = (int*)alloc((size_t)n * 4);
    int* bsum   = (int*)alloc(512 * 4);
    int* row    = (int*)alloc((size_t)(n + 1) * 4);
    int* cursor = (int*)alloc((size_t)n * 4);
    int* gcurb  = (int*)alloc(NBMAX * 4);
    int2* mid   = (int2*)alloc((size_t)E * 8);
    int2* ep    = (int2*)alloc((size_t)E * 8);
    int4* pk_in   = (int4*)alloc(4 * 128 * 16);
    int4* pk_skip = (int4*)alloc(3 * 8 * 128 * 16);
    int4* pk_qkv  = (int4*)alloc((size_t)3 * 24 * 128 * 16);
    float* gsum = (float*)alloc((NGRAPH * 64 * 2 + NGRAPH) * 4);
    unsigned int* gmaxu = (unsigned int*)(gsum + NGRAPH * 64);
    float* cnt  = gsum + NGRAPH * 128;

    int nb4 = (n + 3) / 4;
    int nb64 = (n + 63) / 64;
    int nbs = (n + 255) / 256;
    int ebs = (E + 255) / 256;
    int nbkt = (n + NPB - 1) >> 10;

    k_cvt<<<25, 256, 0, stream>>>(in_W, W_skip, W_qkv, pk_in, pk_skip, pk_qkv);
    hipMemsetAsync(deg, 0, (size_t)n * 4, stream);
    hipMemsetAsync(gsum, 0, (NGRAPH * 64 * 2 + NGRAPH) * 4, stream);
    k_hist<<<ebs, 256, 0, stream>>>(dst, deg, E);
    k_scan1<<<nbs, 256, 0, stream>>>(deg, excl, bsum, n);
    k_scan2<<<1, 512, 0, stream>>>(bsum, nbs);
    k_scan3<<<nbs, 256, 0, stream>>>(excl, bsum, row, cursor, gcurb, n, E);
    k_bucket<<<(E + 4095) / 4096, 256, 0, stream>>>(src, dst, ea, gcurb, mid, E, nbkt);
    k_local<<<dim3(nbkt, 4), 256, 0, stream>>>(row, cursor, mid, ep, n);

    k_in_qkv<<<nb64, 256, 0, stream>>>(x, pk_in, in_b, in_lng, in_lnb,
                                       pk_qkv, b_qkv, h, qh, kvh, n);

    for (int l = 0; l < LAYERS; l++) {
        k_attn<<<nb4, 256, 0, stream>>>(qh, kvh, row, ep, W_edge + l * 64, oacc, n);
        if (l + 1 < LAYERS) {
            k_node_qkv<1><<<nb64, 256, 0, stream>>>(
                h, oacc, pk_skip + l * 1024, b_skip + l * 64,
                W_beta + l * 192, ln_g + l * 64, ln_b + l * 64,
                pk_qkv + (size_t)(l + 1) * 3072, b_qkv + (size_t)(l + 1) * 192,
                qh, kvh, nullptr, nullptr, nullptr, nullptr, n);
        } else {
            k_node_qkv<0><<<nb64, 256, 0, stream>>>(
                h, oacc, pk_skip + l * 1024, b_skip + l * 64,
                W_beta + l * 192, ln_g + l * 64, ln_b + l * 64,
                nullptr, nullptr, nullptr, nullptr,
                batch, gsum, gmaxu, cnt, n);
        }
    }

    k_final<<<NGRAPH, 64, 0, stream>>>(gsum, gmaxu, cnt, r1_W, r1_b, r2_W, r2_b,
                                       r3_W, r3_b, (float*)d_out);
}